// Round 17
// baseline (197.952 us; speedup 1.0000x reference)
//
#include <hip/hip_runtime.h>
#include <cstddef>

#define N_NODES 50000
#define N_EDGES 800000
#define FIN     128
#define NH      4
#define FOUT    16
#define COUT    64   // NH*FOUT
#define STRIPS  (N_NODES / 16)                // 3125
#define PAIRS   ((STRIPS + 1) / 2)            // 1563 (last pair: strip1 invalid)
#define SCAN_BLOCKS ((N_NODES + 255) / 256)   // 196
#define NB      128                            // histogram chunks
#define CHUNK   (N_EDGES / NB)                 // 6250 (exact)
#define HW4     (N_NODES / 4)                  // 12500 packed u8x4 words
#define HALFW   (HW4 / 2)                      // 6250 words per node-half
#define HBYTES2 (HALFW * 4)                    // 25 KB dynamic LDS (half-range)
#define NQ      4                               // colscan quarters
#define BPQ     (NB / NQ)                       // 32 blocks per quarter
#define E4      (N_EDGES / 4)                   // 200000
#define E4B     ((E4 + 255) / 256)              // 782

typedef __bf16 bf16x8 __attribute__((ext_vector_type(8)));
typedef float  f32x4  __attribute__((ext_vector_type(4)));

// ---------------------------------------------------------------------------
// K1: MFMA projection, 2 strips (32 rows) per wave (round-12 win: ~20->~13us;
// B-fragments shared, 2x A-loads in flight). One wave per (strip-pair, half).
// MFMA 16x16x32 layouts (m89/m91): A row=lane&15, k=(lane>>4)*8+e;
// B col=lane&15; D col=lane&15, row=(lane>>4)*4+reg. Tail strip: clamped
// loads + guarded stores. Round-9 post-mortem: B from the one-time bf16
// table wb (f32-direct cost +17us). Round-5: don't fuse edge work here.
// ---------------------------------------------------------------------------
__global__ __launch_bounds__(256) void k1_mfma(
    const float* __restrict__ x, const __bf16* __restrict__ wb,
    const float* __restrict__ asrc, const float* __restrict__ atrg,
    __bf16* __restrict__ projb, float* __restrict__ ssrc, float* __restrict__ strg,
    float* __restrict__ outv)
{
    const int lane = threadIdx.x & 63;
    const int wid  = blockIdx.x * 4 + (threadIdx.x >> 6);
    const int pair = wid >> 1;
    const int half = wid & 1;
    if (pair >= PAIRS) return;
    const int r = lane & 15;
    const int g = lane >> 4;
    const int row0 = pair * 32;

    bf16x8 bfr[4][4];
    #pragma unroll
    for (int j = 0; j < 4; ++j) {
        const __bf16* wrow = wb + (size_t)(half * 64 + j * 16 + r) * FIN;
        #pragma unroll
        for (int kk = 0; kk < 4; ++kk)
            bfr[j][kk] = *reinterpret_cast<const bf16x8*>(wrow + kk * 32 + g * 8);
    }

    const int rowA0 = row0 + r;
    int rowA1 = row0 + 16 + r;
    if (rowA1 >= N_NODES) rowA1 = N_NODES - 1;
    const float* xr0 = x + (size_t)rowA0 * FIN + g * 8;
    const float* xr1 = x + (size_t)rowA1 * FIN + g * 8;
    bf16x8 af0[4], af1[4];
    #pragma unroll
    for (int kk = 0; kk < 4; ++kk) {
        float4 u0 = *reinterpret_cast<const float4*>(xr0 + kk * 32);
        float4 u1 = *reinterpret_cast<const float4*>(xr0 + kk * 32 + 4);
        float4 v0 = *reinterpret_cast<const float4*>(xr1 + kk * 32);
        float4 v1 = *reinterpret_cast<const float4*>(xr1 + kk * 32 + 4);
        bf16x8 a, b;
        a[0] = (__bf16)u0.x; a[1] = (__bf16)u0.y;
        a[2] = (__bf16)u0.z; a[3] = (__bf16)u0.w;
        a[4] = (__bf16)u1.x; a[5] = (__bf16)u1.y;
        a[6] = (__bf16)u1.z; a[7] = (__bf16)u1.w;
        b[0] = (__bf16)v0.x; b[1] = (__bf16)v0.y;
        b[2] = (__bf16)v0.z; b[3] = (__bf16)v0.w;
        b[4] = (__bf16)v1.x; b[5] = (__bf16)v1.y;
        b[6] = (__bf16)v1.z; b[7] = (__bf16)v1.w;
        af0[kk] = a; af1[kk] = b;
    }

    f32x4 acc0[4] = {{0.f,0.f,0.f,0.f},{0.f,0.f,0.f,0.f},
                     {0.f,0.f,0.f,0.f},{0.f,0.f,0.f,0.f}};
    f32x4 acc1[4] = {{0.f,0.f,0.f,0.f},{0.f,0.f,0.f,0.f},
                     {0.f,0.f,0.f,0.f},{0.f,0.f,0.f,0.f}};
    #pragma unroll
    for (int kk = 0; kk < 4; ++kk)
        #pragma unroll
        for (int j = 0; j < 4; ++j) {
            acc0[j] = __builtin_amdgcn_mfma_f32_16x16x32_bf16(
                          af0[kk], bfr[j][kk], acc0[j], 0, 0, 0);
            acc1[j] = __builtin_amdgcn_mfma_f32_16x16x32_bf16(
                          af1[kk], bfr[j][kk], acc1[j], 0, 0, 0);
        }

    if (!half) {
        #pragma unroll
        for (int j = 0; j < 4; ++j)
            #pragma unroll
            for (int q = 0; q < 4; ++q) {
                int n0 = row0 + g * 4 + q;
                int n1 = n0 + 16;
                projb[(size_t)n0 * COUT + j * 16 + r] = (__bf16)acc0[j][q];
                if (n1 < N_NODES)
                    projb[(size_t)n1 * COUT + j * 16 + r] = (__bf16)acc1[j][q];
            }
        #pragma unroll
        for (int j = 0; j < 4; ++j) {
            const float as = asrc[j * 16 + r];
            const float at = atrg[j * 16 + r];
            #pragma unroll
            for (int q = 0; q < 4; ++q) {
                float ts0 = acc0[j][q] * as, tt0 = acc0[j][q] * at;
                float ts1 = acc1[j][q] * as, tt1 = acc1[j][q] * at;
                ts0 += __shfl_xor(ts0, 1); ts0 += __shfl_xor(ts0, 2);
                ts0 += __shfl_xor(ts0, 4); ts0 += __shfl_xor(ts0, 8);
                tt0 += __shfl_xor(tt0, 1); tt0 += __shfl_xor(tt0, 2);
                tt0 += __shfl_xor(tt0, 4); tt0 += __shfl_xor(tt0, 8);
                ts1 += __shfl_xor(ts1, 1); ts1 += __shfl_xor(ts1, 2);
                ts1 += __shfl_xor(ts1, 4); ts1 += __shfl_xor(ts1, 8);
                tt1 += __shfl_xor(tt1, 1); tt1 += __shfl_xor(tt1, 2);
                tt1 += __shfl_xor(tt1, 4); tt1 += __shfl_xor(tt1, 8);
                if (r == 0) {
                    int n0 = row0 + g * 4 + q;
                    int n1 = n0 + 16;
                    ssrc[(size_t)n0 * NH + j] = ts0;
                    strg[(size_t)n0 * NH + j] = tt0;
                    if (n1 < N_NODES) {
                        ssrc[(size_t)n1 * NH + j] = ts1;
                        strg[(size_t)n1 * NH + j] = tt1;
                    }
                }
            }
        }
    } else {
        #pragma unroll
        for (int j = 0; j < 4; ++j)
            #pragma unroll
            for (int q = 0; q < 4; ++q) {
                int n0 = row0 + g * 4 + q;
                int n1 = n0 + 16;
                outv[(size_t)n0 * COUT + j * 16 + r] = acc0[j][q];
                if (n1 < N_NODES)
                    outv[(size_t)n1 * COUT + j * 16 + r] = acc1[j][q];
            }
    }
}

// ---------------------------------------------------------------------------
// CSR build pass 1 (node-half split, round 15). Grid NB*2+1: block (c,v)
// histograms chunk c filtered to node half v; 25KB LDS. Block NB*2 packs
// weights + resets scounter. u8x4-packed counts (per-(block,node) max ~6,
// deg max ~45, seed-0 uniform -> no byte-lane carry). LDS atomicAdd return
// IS the local rank (round 10). Round-6: global atomics = 46us; avoided.
// ---------------------------------------------------------------------------
__global__ __launch_bounds__(1024) void k_hist(
    const int* __restrict__ ei, unsigned* __restrict__ histG,
    unsigned char* __restrict__ rank,
    const float* __restrict__ wproj, const float* __restrict__ wskip,
    __bf16* __restrict__ wb, int* __restrict__ scounter)
{
    if (blockIdx.x == NB * 2) {
        const int tid = threadIdx.x;
        if (tid == 0) *scounter = 0;
        for (int gid = tid; gid < (128 * FIN) / 4; gid += 1024) {
            int row = gid >> 5;
            float4 v = (row < 64)
                ? reinterpret_cast<const float4*>(wproj)[gid]
                : reinterpret_cast<const float4*>(wskip)[gid - 2048];
            __bf16* o = wb + (size_t)gid * 4;
            o[0] = (__bf16)v.x; o[1] = (__bf16)v.y;
            o[2] = (__bf16)v.z; o[3] = (__bf16)v.w;
        }
        return;
    }
    extern __shared__ unsigned h[];               // HALFW words (25KB)
    const int chunk = blockIdx.x >> 1;
    const int vhalf = blockIdx.x & 1;
    const int t = threadIdx.x;
    for (int i = t; i < HALFW; i += 1024) h[i] = 0;
    __syncthreads();
    const int base = chunk * CHUNK;
    const int plo  = vhalf * HALFW;               // first quad of this half
    for (int i = t; i < CHUNK; i += 1024) {
        int tg = ei[N_EDGES + base + i];
        int p  = (tg >> 2) - plo;
        if ((unsigned)p < (unsigned)HALFW) {      // tg in this node half
            int sh = (tg & 3) * 8;
            unsigned old = atomicAdd(&h[p], 1u << sh);
            rank[base + i] = (unsigned char)((old >> sh) & 0xffu);
        }
    }
    __syncthreads();
    unsigned* out = histG + (size_t)chunk * HW4 + plo;
    for (int i = t; i < HALFW; i += 1024) out[i] = h[i];
}

// ---------------------------------------------------------------------------
// Fused CSR pass 2 (round-16: quarter-base folded into offG; baseQ deleted).
// Pass 1: quarter totals; LDS exchange; pass 2 re-reads histG L2-hot, stores
// run+pre. Then 256-wide node scan -> tmpExc/bsum; last-block-done bOff.
// ---------------------------------------------------------------------------
__global__ __launch_bounds__(256) void k_csr_scan(
    const unsigned* __restrict__ histG, unsigned* __restrict__ offG,
    int* __restrict__ deg, int* __restrict__ tmpExc,
    int* __restrict__ bsum, int* __restrict__ bOff,
    int* __restrict__ scounter)
{
    __shared__ unsigned part[64][NQ];
    __shared__ int sm[256];
    __shared__ int isLast;
    const int t  = threadIdx.x;
    const int pl = t >> 2;                        // quad within block
    const int q  = t & 3;                         // quarter
    const int p  = blockIdx.x * 64 + pl;
    const bool valid = (p < HW4);

    unsigned tot = 0;
    if (valid) {
        #pragma unroll 4
        for (int b = q * BPQ; b < (q + 1) * BPQ; ++b)
            tot += histG[(size_t)b * HW4 + p];     // u8 lanes, no carry
    }
    part[pl][q] = tot;
    __syncthreads();

    unsigned p0 = part[pl][0], p1 = part[pl][1],
             p2 = part[pl][2], p3 = part[pl][3];
    unsigned pre = (q > 0 ? p0 : 0u) + (q > 1 ? p1 : 0u) + (q > 2 ? p2 : 0u);
    unsigned total = p0 + p1 + p2 + p3;           // packed degrees, no carry

    if (valid) {
        unsigned acc = pre;
        #pragma unroll 4
        for (int b = q * BPQ; b < (q + 1) * BPQ; ++b) {
            unsigned v = histG[(size_t)b * HW4 + p];
            offG[(size_t)b * HW4 + p] = acc;
            acc += v;
        }
        if (q == 0)
            reinterpret_cast<int4*>(deg)[p] =
                make_int4((int)(total & 0xffu), (int)((total >> 8) & 0xffu),
                          (int)((total >> 16) & 0xffu), (int)(total >> 24));
    }
    sm[t] = valid ? (int)((total >> (q * 8)) & 0xffu) : 0;
    __syncthreads();
    int v = sm[t];
    #pragma unroll
    for (int off = 1; off < 256; off <<= 1) {
        int x = (t >= off) ? sm[t - off] : 0;
        __syncthreads();
        sm[t] += x;
        __syncthreads();
    }
    int i = blockIdx.x * 256 + t;
    if (i < N_NODES) tmpExc[i] = sm[t] - v;
    if (t == 255) atomicExch(&bsum[blockIdx.x], sm[t]);  // device-scope publish
    __syncthreads();
    if (t == 0) {
        __threadfence();
        int old = atomicAdd(scounter, 1);
        isLast = (old == SCAN_BLOCKS - 1) ? 1 : 0;
    }
    __syncthreads();
    if (isLast) {
        int bv = (t < SCAN_BLOCKS) ? atomicAdd(&bsum[t], 0) : 0;  // atomic read
        sm[t] = bv;
        __syncthreads();
        #pragma unroll
        for (int off = 1; off < 256; off <<= 1) {
            int x = (t >= off) ? sm[t - off] : 0;
            __syncthreads();
            sm[t] += x;
            __syncthreads();
        }
        if (t < SCAN_BLOCKS) bOff[t] = sm[t] - bv;
    }
}

// ---------------------------------------------------------------------------
// CSR build pass 3: 4 edges/thread, slot = tmpExc + bOff + cross + rank.
// One random gather (offG base-folded, round 16). Plain stores, no LDS.
// ---------------------------------------------------------------------------
__global__ __launch_bounds__(256) void k_scatter(
    const int* __restrict__ ei, const unsigned char* __restrict__ rank,
    const unsigned* __restrict__ offG,
    const int* __restrict__ tmpExc, const int* __restrict__ bOff,
    int* __restrict__ srcs)
{
    int e4 = blockIdx.x * 256 + threadIdx.x;
    if (e4 >= E4) return;
    int4 s4 = reinterpret_cast<const int4*>(ei)[e4];
    int4 t4 = reinterpret_cast<const int4*>(ei + N_EDGES)[e4];
    uchar4 r4 = reinterpret_cast<const uchar4*>(rank)[e4];
    const int e0 = e4 * 4;
    int ss[4] = {s4.x, s4.y, s4.z, s4.w};
    int tt[4] = {t4.x, t4.y, t4.z, t4.w};
    int rr[4] = {r4.x, r4.y, r4.z, r4.w};
    #pragma unroll
    for (int u = 0; u < 4; ++u) {
        int tg = tt[u];
        int b  = (e0 + u) / CHUNK;                 // magic-mul division
        int sh = (tg & 3) * 8;
        unsigned cw = offG[(size_t)b * HW4 + (tg >> 2)];
        int cross = (int)((cw >> sh) & 0xffu);
        int slot  = tmpExc[tg] + bOff[tg >> 8] + cross + rr[u];
        srcs[slot] = ss[u];
    }
}

// ---------------------------------------------------------------------------
// K3: fused gather-softmax-aggregate-skip-ELU (round-10/11 structure;
// round-12: do NOT split per-node work across waves).
// Round-17: TA-issue reduction — k3 issues ~2.4M vector loads (~15.6us of
// pure VMEM-issue at 1/4cyc/CU), so the per-edge ssrc gather (wave-uniform
// 16B row, only h=lane>>4 varies) is moved to the SCALAR path: readfirstlane
// the src id, s_load the float4, select by h with cndmask. Halves the
// vector-load count; projb's 128B row gather (per-lane data) remains.
// Bit-identical values. srcs-id prefetch (round 16) kept.
// ---------------------------------------------------------------------------
__global__ __launch_bounds__(256) void k3_gather(
    const int* __restrict__ tmpExc, const int* __restrict__ bOff,
    const int* __restrict__ deg, const int* __restrict__ srcs,
    const float* __restrict__ ssrc, const float* __restrict__ strg,
    const __bf16* __restrict__ projb, float* __restrict__ outv)
{
    const int lane = threadIdx.x & 63;
    const int node = __builtin_amdgcn_readfirstlane(blockIdx.x * 4 + (threadIdx.x >> 6));
    if (node >= N_NODES) return;
    const int h = lane >> 4;
    const bool hb0 = (h & 1) != 0;
    const bool hb1 = (h & 2) != 0;
    const int begin = tmpExc[node] + bOff[node >> 8];
    const int dg    = deg[node];
    const float st  = strg[(size_t)node * NH + h];
    const float skip = outv[(size_t)node * COUT + lane];

    float acc = 0.f, dsum = 0.f;
    int i = 0;
    const int nch = dg >> 3;                      // 8-edge chunks
    if (nch > 0) {
        int s[8];
        #pragma unroll
        for (int u = 0; u < 8; ++u)
            s[u] = __builtin_amdgcn_readfirstlane(srcs[begin + u]);
        for (int c = 0; c < nch; ++c) {
            // scalar-path ssrc rows (s_load_dwordx4; no TA slot)
            float4 sv[8];
            #pragma unroll
            for (int u = 0; u < 8; ++u)
                sv[u] = *reinterpret_cast<const float4*>(ssrc + (size_t)s[u] * NH);
            // vector-path projb row gathers (irreducible: per-lane data)
            float pp[8];
            #pragma unroll
            for (int u = 0; u < 8; ++u)
                pp[u] = (float)projb[(size_t)s[u] * COUT + lane];
            int sn[8];
            if (c + 1 < nch) {                    // wave-uniform guard
                #pragma unroll
                for (int u = 0; u < 8; ++u)
                    sn[u] = __builtin_amdgcn_readfirstlane(srcs[begin + (c + 1) * 8 + u]);
            } else {
                #pragma unroll
                for (int u = 0; u < 8; ++u) sn[u] = s[u];
            }
            #pragma unroll
            for (int u = 0; u < 8; ++u) {
                float ax = hb0 ? sv[u].y : sv[u].x;
                float ay = hb0 ? sv[u].w : sv[u].z;
                float z  = (hb1 ? ay : ax) + st;
                z = (z >= 0.f) ? z : 0.2f * z;
                float ez = __expf(z);
                dsum += ez;
                acc += ez * pp[u];
            }
            #pragma unroll
            for (int u = 0; u < 8; ++u) s[u] = sn[u];
        }
        i = nch * 8;
    }
    for (; i + 4 <= dg; i += 4) {
        int s[4]; float4 sv[4]; float pp[4];
        #pragma unroll
        for (int u = 0; u < 4; ++u)
            s[u] = __builtin_amdgcn_readfirstlane(srcs[begin + i + u]);
        #pragma unroll
        for (int u = 0; u < 4; ++u)
            sv[u] = *reinterpret_cast<const float4*>(ssrc + (size_t)s[u] * NH);
        #pragma unroll
        for (int u = 0; u < 4; ++u)
            pp[u] = (float)projb[(size_t)s[u] * COUT + lane];
        #pragma unroll
        for (int u = 0; u < 4; ++u) {
            float ax = hb0 ? sv[u].y : sv[u].x;
            float ay = hb0 ? sv[u].w : sv[u].z;
            float z  = (hb1 ? ay : ax) + st;
            z = (z >= 0.f) ? z : 0.2f * z;
            float ez = __expf(z);
            dsum += ez;
            acc += ez * pp[u];
        }
    }
    for (; i < dg; ++i) {
        int s = __builtin_amdgcn_readfirstlane(srcs[begin + i]);
        float4 sv = *reinterpret_cast<const float4*>(ssrc + (size_t)s * NH);
        float ax = hb0 ? sv.y : sv.x;
        float ay = hb0 ? sv.w : sv.z;
        float z  = (hb1 ? ay : ax) + st;
        z = (z >= 0.f) ? z : 0.2f * z;
        float ez = __expf(z);
        float p  = (float)projb[(size_t)s * COUT + lane];
        dsum += ez;
        acc += ez * p;
    }
    float o = acc / (dsum + 1e-16f) + skip;
    o = (o > 0.f) ? o : expm1f(o);
    outv[(size_t)node * COUT + lane] = o;
}

extern "C" void kernel_launch(void* const* d_in, const int* in_sizes, int n_in,
                              void* d_out, int out_size, void* d_ws, size_t ws_size,
                              hipStream_t stream)
{
    const float* x     = (const float*)d_in[0];
    const int*   ei    = (const int*)  d_in[1];   // [2, E] int32
    const float* wproj = (const float*)d_in[2];
    const float* asrc  = (const float*)d_in[3];
    const float* atrg  = (const float*)d_in[4];
    const float* wskip = (const float*)d_in[5];
    float* outv = (float*)d_out;

    // workspace layout
    __bf16* projb = (__bf16*)d_ws;                        // N*64 bf16 (in N*64 f32 slot)
    float* base  = (float*)d_ws;
    float* ssrc  = base + (size_t)N_NODES * COUT;         // N*4
    float* strg  = ssrc + (size_t)N_NODES * NH;           // N*4
    int* deg     = (int*)(strg + (size_t)N_NODES * NH);   // N (int4-aligned)
    int* tmpExc  = deg    + N_NODES;                      // N
    int* bsum    = tmpExc + N_NODES;                      // 256
    int* bOff    = bsum   + 256;                          // 256
    int* srcs    = bOff   + 256;                          // E
    unsigned* histG   = (unsigned*)(srcs + N_EDGES);      // NB*HW4
    unsigned* offG    = histG + (size_t)NB * HW4;         // NB*HW4 (base-folded)
    unsigned char* rank = (unsigned char*)(offG + (size_t)NB * HW4); // E u8
    __bf16* wb   = (__bf16*)(rank + N_EDGES);             // 128*128 bf16
    int* scounter = (int*)(wb + 128 * FIN);               // 1

    // pass 1: histogram + rank, node-half split (+ weight pack / counter
    // reset in block NB*2)
    k_hist<<<NB * 2 + 1, 1024, HBYTES2, stream>>>(ei, histG, rank,
                                                  wproj, wskip, wb, scounter);

    int k1_blocks = (PAIRS * 2 + 3) / 4;   // 782
    k1_mfma<<<k1_blocks, 256, 0, stream>>>(x, wb, asrc, atrg,
                                           projb, ssrc, strg, outv);

    // pass 2: fused colscan (base-folded offsets) + node scan + bOff
    k_csr_scan<<<SCAN_BLOCKS, 256, 0, stream>>>(histG, offG, deg,
                                                tmpExc, bsum, bOff, scounter);

    k_scatter<<<E4B, 256, 0, stream>>>(ei, rank, offG,
                                       tmpExc, bOff, srcs);

    int k3_blocks = (N_NODES + 3) / 4;   // 12500, one wave per node
    k3_gather<<<k3_blocks, 256, 0, stream>>>(tmpExc, bOff, deg, srcs,
                                             ssrc, strg, projb, outv);
}

// Round 18
// 92.493 us; speedup vs baseline: 2.1402x; 2.1402x over previous
//
#include <hip/hip_runtime.h>
#include <cstddef>

#define N_NODES 50000
#define N_EDGES 800000
#define FIN     128
#define NH      4
#define FOUT    16
#define COUT    64   // NH*FOUT
#define STRIPS  (N_NODES / 16)                // 3125
#define PAIRS   ((STRIPS + 1) / 2)            // 1563 (last pair: strip1 invalid)
#define SCAN_BLOCKS ((N_NODES + 255) / 256)   // 196
#define NB      128                            // histogram chunks
#define CHUNK   (N_EDGES / NB)                 // 6250 (exact)
#define HW4     (N_NODES / 4)                  // 12500 packed u8x4 words
#define HALFW   (HW4 / 2)                      // 6250 words per node-half
#define HBYTES2 (HALFW * 4)                    // 25 KB dynamic LDS (half-range)
#define NQ      4                               // colscan quarters
#define BPQ     (NB / NQ)                       // 32 blocks per quarter
#define E4      (N_EDGES / 4)                   // 200000
#define E4B     ((E4 + 255) / 256)              // 782

typedef __bf16 bf16x8 __attribute__((ext_vector_type(8)));
typedef float  f32x4  __attribute__((ext_vector_type(4)));

// ---------------------------------------------------------------------------
// K1: MFMA projection, 2 strips (32 rows) per wave (round-12 win: ~20->~13us;
// B-fragments shared, 2x A-loads in flight). One wave per (strip-pair, half).
// MFMA 16x16x32 layouts (m89/m91): A row=lane&15, k=(lane>>4)*8+e;
// B col=lane&15; D col=lane&15, row=(lane>>4)*4+reg. Tail strip: clamped
// loads + guarded stores. Round-9 post-mortem: B from the one-time bf16
// table wb (f32-direct cost +17us). Round-5: don't fuse edge work here.
// ---------------------------------------------------------------------------
__global__ __launch_bounds__(256) void k1_mfma(
    const float* __restrict__ x, const __bf16* __restrict__ wb,
    const float* __restrict__ asrc, const float* __restrict__ atrg,
    __bf16* __restrict__ projb, float* __restrict__ ssrc, float* __restrict__ strg,
    float* __restrict__ outv)
{
    const int lane = threadIdx.x & 63;
    const int wid  = blockIdx.x * 4 + (threadIdx.x >> 6);
    const int pair = wid >> 1;
    const int half = wid & 1;
    if (pair >= PAIRS) return;
    const int r = lane & 15;
    const int g = lane >> 4;
    const int row0 = pair * 32;

    bf16x8 bfr[4][4];
    #pragma unroll
    for (int j = 0; j < 4; ++j) {
        const __bf16* wrow = wb + (size_t)(half * 64 + j * 16 + r) * FIN;
        #pragma unroll
        for (int kk = 0; kk < 4; ++kk)
            bfr[j][kk] = *reinterpret_cast<const bf16x8*>(wrow + kk * 32 + g * 8);
    }

    const int rowA0 = row0 + r;
    int rowA1 = row0 + 16 + r;
    if (rowA1 >= N_NODES) rowA1 = N_NODES - 1;
    const float* xr0 = x + (size_t)rowA0 * FIN + g * 8;
    const float* xr1 = x + (size_t)rowA1 * FIN + g * 8;
    bf16x8 af0[4], af1[4];
    #pragma unroll
    for (int kk = 0; kk < 4; ++kk) {
        float4 u0 = *reinterpret_cast<const float4*>(xr0 + kk * 32);
        float4 u1 = *reinterpret_cast<const float4*>(xr0 + kk * 32 + 4);
        float4 v0 = *reinterpret_cast<const float4*>(xr1 + kk * 32);
        float4 v1 = *reinterpret_cast<const float4*>(xr1 + kk * 32 + 4);
        bf16x8 a, b;
        a[0] = (__bf16)u0.x; a[1] = (__bf16)u0.y;
        a[2] = (__bf16)u0.z; a[3] = (__bf16)u0.w;
        a[4] = (__bf16)u1.x; a[5] = (__bf16)u1.y;
        a[6] = (__bf16)u1.z; a[7] = (__bf16)u1.w;
        b[0] = (__bf16)v0.x; b[1] = (__bf16)v0.y;
        b[2] = (__bf16)v0.z; b[3] = (__bf16)v0.w;
        b[4] = (__bf16)v1.x; b[5] = (__bf16)v1.y;
        b[6] = (__bf16)v1.z; b[7] = (__bf16)v1.w;
        af0[kk] = a; af1[kk] = b;
    }

    f32x4 acc0[4] = {{0.f,0.f,0.f,0.f},{0.f,0.f,0.f,0.f},
                     {0.f,0.f,0.f,0.f},{0.f,0.f,0.f,0.f}};
    f32x4 acc1[4] = {{0.f,0.f,0.f,0.f},{0.f,0.f,0.f,0.f},
                     {0.f,0.f,0.f,0.f},{0.f,0.f,0.f,0.f}};
    #pragma unroll
    for (int kk = 0; kk < 4; ++kk)
        #pragma unroll
        for (int j = 0; j < 4; ++j) {
            acc0[j] = __builtin_amdgcn_mfma_f32_16x16x32_bf16(
                          af0[kk], bfr[j][kk], acc0[j], 0, 0, 0);
            acc1[j] = __builtin_amdgcn_mfma_f32_16x16x32_bf16(
                          af1[kk], bfr[j][kk], acc1[j], 0, 0, 0);
        }

    if (!half) {
        #pragma unroll
        for (int j = 0; j < 4; ++j)
            #pragma unroll
            for (int q = 0; q < 4; ++q) {
                int n0 = row0 + g * 4 + q;
                int n1 = n0 + 16;
                projb[(size_t)n0 * COUT + j * 16 + r] = (__bf16)acc0[j][q];
                if (n1 < N_NODES)
                    projb[(size_t)n1 * COUT + j * 16 + r] = (__bf16)acc1[j][q];
            }
        #pragma unroll
        for (int j = 0; j < 4; ++j) {
            const float as = asrc[j * 16 + r];
            const float at = atrg[j * 16 + r];
            #pragma unroll
            for (int q = 0; q < 4; ++q) {
                float ts0 = acc0[j][q] * as, tt0 = acc0[j][q] * at;
                float ts1 = acc1[j][q] * as, tt1 = acc1[j][q] * at;
                ts0 += __shfl_xor(ts0, 1); ts0 += __shfl_xor(ts0, 2);
                ts0 += __shfl_xor(ts0, 4); ts0 += __shfl_xor(ts0, 8);
                tt0 += __shfl_xor(tt0, 1); tt0 += __shfl_xor(tt0, 2);
                tt0 += __shfl_xor(tt0, 4); tt0 += __shfl_xor(tt0, 8);
                ts1 += __shfl_xor(ts1, 1); ts1 += __shfl_xor(ts1, 2);
                ts1 += __shfl_xor(ts1, 4); ts1 += __shfl_xor(ts1, 8);
                tt1 += __shfl_xor(tt1, 1); tt1 += __shfl_xor(tt1, 2);
                tt1 += __shfl_xor(tt1, 4); tt1 += __shfl_xor(tt1, 8);
                if (r == 0) {
                    int n0 = row0 + g * 4 + q;
                    int n1 = n0 + 16;
                    ssrc[(size_t)n0 * NH + j] = ts0;
                    strg[(size_t)n0 * NH + j] = tt0;
                    if (n1 < N_NODES) {
                        ssrc[(size_t)n1 * NH + j] = ts1;
                        strg[(size_t)n1 * NH + j] = tt1;
                    }
                }
            }
        }
    } else {
        #pragma unroll
        for (int j = 0; j < 4; ++j)
            #pragma unroll
            for (int q = 0; q < 4; ++q) {
                int n0 = row0 + g * 4 + q;
                int n1 = n0 + 16;
                outv[(size_t)n0 * COUT + j * 16 + r] = acc0[j][q];
                if (n1 < N_NODES)
                    outv[(size_t)n1 * COUT + j * 16 + r] = acc1[j][q];
            }
    }
}

// ---------------------------------------------------------------------------
// CSR build pass 1 (node-half split, round 15). Grid NB*2+1: block (c,v)
// histograms chunk c filtered to node half v; 25KB LDS. Block NB*2 packs
// weights + resets scounter. u8x4-packed counts (per-(block,node) max ~6,
// deg max ~45, seed-0 uniform -> no byte-lane carry). LDS atomicAdd return
// IS the local rank (round 10). Round-6: global atomics = 46us; avoided.
// ---------------------------------------------------------------------------
__global__ __launch_bounds__(1024) void k_hist(
    const int* __restrict__ ei, unsigned* __restrict__ histG,
    unsigned char* __restrict__ rank,
    const float* __restrict__ wproj, const float* __restrict__ wskip,
    __bf16* __restrict__ wb, int* __restrict__ scounter)
{
    if (blockIdx.x == NB * 2) {
        const int tid = threadIdx.x;
        if (tid == 0) *scounter = 0;
        for (int gid = tid; gid < (128 * FIN) / 4; gid += 1024) {
            int row = gid >> 5;
            float4 v = (row < 64)
                ? reinterpret_cast<const float4*>(wproj)[gid]
                : reinterpret_cast<const float4*>(wskip)[gid - 2048];
            __bf16* o = wb + (size_t)gid * 4;
            o[0] = (__bf16)v.x; o[1] = (__bf16)v.y;
            o[2] = (__bf16)v.z; o[3] = (__bf16)v.w;
        }
        return;
    }
    extern __shared__ unsigned h[];               // HALFW words (25KB)
    const int chunk = blockIdx.x >> 1;
    const int vhalf = blockIdx.x & 1;
    const int t = threadIdx.x;
    for (int i = t; i < HALFW; i += 1024) h[i] = 0;
    __syncthreads();
    const int base = chunk * CHUNK;
    const int plo  = vhalf * HALFW;               // first quad of this half
    for (int i = t; i < CHUNK; i += 1024) {
        int tg = ei[N_EDGES + base + i];
        int p  = (tg >> 2) - plo;
        if ((unsigned)p < (unsigned)HALFW) {      // tg in this node half
            int sh = (tg & 3) * 8;
            unsigned old = atomicAdd(&h[p], 1u << sh);
            rank[base + i] = (unsigned char)((old >> sh) & 0xffu);
        }
    }
    __syncthreads();
    unsigned* out = histG + (size_t)chunk * HW4 + plo;
    for (int i = t; i < HALFW; i += 1024) out[i] = h[i];
}

// ---------------------------------------------------------------------------
// Fused CSR pass 2 (round-16: quarter-base folded into offG; baseQ deleted).
// Pass 1: quarter totals; LDS exchange; pass 2 re-reads histG L2-hot, stores
// run+pre. Then 256-wide node scan -> tmpExc/bsum; last-block-done bOff.
// ---------------------------------------------------------------------------
__global__ __launch_bounds__(256) void k_csr_scan(
    const unsigned* __restrict__ histG, unsigned* __restrict__ offG,
    int* __restrict__ deg, int* __restrict__ tmpExc,
    int* __restrict__ bsum, int* __restrict__ bOff,
    int* __restrict__ scounter)
{
    __shared__ unsigned part[64][NQ];
    __shared__ int sm[256];
    __shared__ int isLast;
    const int t  = threadIdx.x;
    const int pl = t >> 2;                        // quad within block
    const int q  = t & 3;                         // quarter
    const int p  = blockIdx.x * 64 + pl;
    const bool valid = (p < HW4);

    unsigned tot = 0;
    if (valid) {
        #pragma unroll 4
        for (int b = q * BPQ; b < (q + 1) * BPQ; ++b)
            tot += histG[(size_t)b * HW4 + p];     // u8 lanes, no carry
    }
    part[pl][q] = tot;
    __syncthreads();

    unsigned p0 = part[pl][0], p1 = part[pl][1],
             p2 = part[pl][2], p3 = part[pl][3];
    unsigned pre = (q > 0 ? p0 : 0u) + (q > 1 ? p1 : 0u) + (q > 2 ? p2 : 0u);
    unsigned total = p0 + p1 + p2 + p3;           // packed degrees, no carry

    if (valid) {
        unsigned acc = pre;
        #pragma unroll 4
        for (int b = q * BPQ; b < (q + 1) * BPQ; ++b) {
            unsigned v = histG[(size_t)b * HW4 + p];
            offG[(size_t)b * HW4 + p] = acc;
            acc += v;
        }
        if (q == 0)
            reinterpret_cast<int4*>(deg)[p] =
                make_int4((int)(total & 0xffu), (int)((total >> 8) & 0xffu),
                          (int)((total >> 16) & 0xffu), (int)(total >> 24));
    }
    sm[t] = valid ? (int)((total >> (q * 8)) & 0xffu) : 0;
    __syncthreads();
    int v = sm[t];
    #pragma unroll
    for (int off = 1; off < 256; off <<= 1) {
        int x = (t >= off) ? sm[t - off] : 0;
        __syncthreads();
        sm[t] += x;
        __syncthreads();
    }
    int i = blockIdx.x * 256 + t;
    if (i < N_NODES) tmpExc[i] = sm[t] - v;
    if (t == 255) atomicExch(&bsum[blockIdx.x], sm[t]);  // device-scope publish
    __syncthreads();
    if (t == 0) {
        __threadfence();
        int old = atomicAdd(scounter, 1);
        isLast = (old == SCAN_BLOCKS - 1) ? 1 : 0;
    }
    __syncthreads();
    if (isLast) {
        int bv = (t < SCAN_BLOCKS) ? atomicAdd(&bsum[t], 0) : 0;  // atomic read
        sm[t] = bv;
        __syncthreads();
        #pragma unroll
        for (int off = 1; off < 256; off <<= 1) {
            int x = (t >= off) ? sm[t - off] : 0;
            __syncthreads();
            sm[t] += x;
            __syncthreads();
        }
        if (t < SCAN_BLOCKS) bOff[t] = sm[t] - bv;
    }
}

// ---------------------------------------------------------------------------
// CSR build pass 3: 4 edges/thread, slot = tmpExc + bOff + cross + rank.
// One random gather (offG base-folded, round 16). Plain stores, no LDS.
// ---------------------------------------------------------------------------
__global__ __launch_bounds__(256) void k_scatter(
    const int* __restrict__ ei, const unsigned char* __restrict__ rank,
    const unsigned* __restrict__ offG,
    const int* __restrict__ tmpExc, const int* __restrict__ bOff,
    int* __restrict__ srcs)
{
    int e4 = blockIdx.x * 256 + threadIdx.x;
    if (e4 >= E4) return;
    int4 s4 = reinterpret_cast<const int4*>(ei)[e4];
    int4 t4 = reinterpret_cast<const int4*>(ei + N_EDGES)[e4];
    uchar4 r4 = reinterpret_cast<const uchar4*>(rank)[e4];
    const int e0 = e4 * 4;
    int ss[4] = {s4.x, s4.y, s4.z, s4.w};
    int tt[4] = {t4.x, t4.y, t4.z, t4.w};
    int rr[4] = {r4.x, r4.y, r4.z, r4.w};
    #pragma unroll
    for (int u = 0; u < 4; ++u) {
        int tg = tt[u];
        int b  = (e0 + u) / CHUNK;                 // magic-mul division
        int sh = (tg & 3) * 8;
        unsigned cw = offG[(size_t)b * HW4 + (tg >> 2)];
        int cross = (int)((cw >> sh) & 0xffu);
        int slot  = tmpExc[tg] + bOff[tg >> 8] + cross + rr[u];
        srcs[slot] = ss[u];
    }
}

// ---------------------------------------------------------------------------
// K3: fused gather-softmax-aggregate-skip-ELU — EXACT round-16 form
// (92.6us state). Round-17 post-mortem: forcing the ssrc gather onto the
// scalar path via readfirstlane made the compiler demote the unrolled
// float4 arrays to LDS/scratch (LDS_Block_Size 16K, WRITE 529MB, 5.25M
// bank conflicts, k3 24->140us). Do NOT hand-force scalar loads on loaded
// values; vector gathers + srcs-id prefetch is the measured-fast form.
// FETCH 51MB = 8 XCDs x 6.4MB projb = compulsory minimum (private L2s).
// ---------------------------------------------------------------------------
__global__ __launch_bounds__(256) void k3_gather(
    const int* __restrict__ tmpExc, const int* __restrict__ bOff,
    const int* __restrict__ deg, const int* __restrict__ srcs,
    const float* __restrict__ ssrc, const float* __restrict__ strg,
    const __bf16* __restrict__ projb, float* __restrict__ outv)
{
    const int lane = threadIdx.x & 63;
    const int node = __builtin_amdgcn_readfirstlane(blockIdx.x * 4 + (threadIdx.x >> 6));
    if (node >= N_NODES) return;
    const int h = lane >> 4;
    const int begin = tmpExc[node] + bOff[node >> 8];
    const int dg    = deg[node];
    const float st  = strg[(size_t)node * NH + h];
    const float skip = outv[(size_t)node * COUT + lane];

    float acc = 0.f, dsum = 0.f;
    int i = 0;
    const int nch = dg >> 3;                      // 8-edge chunks
    if (nch > 0) {
        int s[8];
        #pragma unroll
        for (int u = 0; u < 8; ++u) s[u] = srcs[begin + u];
        for (int c = 0; c < nch; ++c) {
            float a[8], pp[8];
            #pragma unroll
            for (int u = 0; u < 8; ++u) a[u] = ssrc[(size_t)s[u] * NH + h];
            #pragma unroll
            for (int u = 0; u < 8; ++u) pp[u] = (float)projb[(size_t)s[u] * COUT + lane];
            int sn[8];
            if (c + 1 < nch) {                    // wave-uniform guard
                #pragma unroll
                for (int u = 0; u < 8; ++u) sn[u] = srcs[begin + (c + 1) * 8 + u];
            } else {
                #pragma unroll
                for (int u = 0; u < 8; ++u) sn[u] = s[u];
            }
            #pragma unroll
            for (int u = 0; u < 8; ++u) {
                float z = a[u] + st;
                z = (z >= 0.f) ? z : 0.2f * z;
                float ez = __expf(z);
                dsum += ez;
                acc += ez * pp[u];
            }
            #pragma unroll
            for (int u = 0; u < 8; ++u) s[u] = sn[u];
        }
        i = nch * 8;
    }
    for (; i + 4 <= dg; i += 4) {
        int s[4]; float a[4], p[4];
        #pragma unroll
        for (int u = 0; u < 4; ++u) s[u] = srcs[begin + i + u];
        #pragma unroll
        for (int u = 0; u < 4; ++u) a[u] = ssrc[(size_t)s[u] * NH + h];
        #pragma unroll
        for (int u = 0; u < 4; ++u) p[u] = (float)projb[(size_t)s[u] * COUT + lane];
        #pragma unroll
        for (int u = 0; u < 4; ++u) {
            float z = a[u] + st;
            z = (z >= 0.f) ? z : 0.2f * z;
            float ez = __expf(z);
            dsum += ez;
            acc += ez * p[u];
        }
    }
    for (; i < dg; ++i) {
        int s = srcs[begin + i];
        float z = ssrc[(size_t)s * NH + h] + st;
        z = (z >= 0.f) ? z : 0.2f * z;
        float ez = __expf(z);
        float p  = (float)projb[(size_t)s * COUT + lane];
        dsum += ez;
        acc += ez * p;
    }
    float o = acc / (dsum + 1e-16f) + skip;
    o = (o > 0.f) ? o : expm1f(o);
    outv[(size_t)node * COUT + lane] = o;
}

extern "C" void kernel_launch(void* const* d_in, const int* in_sizes, int n_in,
                              void* d_out, int out_size, void* d_ws, size_t ws_size,
                              hipStream_t stream)
{
    const float* x     = (const float*)d_in[0];
    const int*   ei    = (const int*)  d_in[1];   // [2, E] int32
    const float* wproj = (const float*)d_in[2];
    const float* asrc  = (const float*)d_in[3];
    const float* atrg  = (const float*)d_in[4];
    const float* wskip = (const float*)d_in[5];
    float* outv = (float*)d_out;

    // workspace layout
    __bf16* projb = (__bf16*)d_ws;                        // N*64 bf16 (in N*64 f32 slot)
    float* base  = (float*)d_ws;
    float* ssrc  = base + (size_t)N_NODES * COUT;         // N*4
    float* strg  = ssrc + (size_t)N_NODES * NH;           // N*4
    int* deg     = (int*)(strg + (size_t)N_NODES * NH);   // N (int4-aligned)
    int* tmpExc  = deg    + N_NODES;                      // N
    int* bsum    = tmpExc + N_NODES;                      // 256
    int* bOff    = bsum   + 256;                          // 256
    int* srcs    = bOff   + 256;                          // E
    unsigned* histG   = (unsigned*)(srcs + N_EDGES);      // NB*HW4
    unsigned* offG    = histG + (size_t)NB * HW4;         // NB*HW4 (base-folded)
    unsigned char* rank = (unsigned char*)(offG + (size_t)NB * HW4); // E u8
    __bf16* wb   = (__bf16*)(rank + N_EDGES);             // 128*128 bf16
    int* scounter = (int*)(wb + 128 * FIN);               // 1

    // pass 1: histogram + rank, node-half split (+ weight pack / counter
    // reset in block NB*2)
    k_hist<<<NB * 2 + 1, 1024, HBYTES2, stream>>>(ei, histG, rank,
                                                  wproj, wskip, wb, scounter);

    int k1_blocks = (PAIRS * 2 + 3) / 4;   // 782
    k1_mfma<<<k1_blocks, 256, 0, stream>>>(x, wb, asrc, atrg,
                                           projb, ssrc, strg, outv);

    // pass 2: fused colscan (base-folded offsets) + node scan + bOff
    k_csr_scan<<<SCAN_BLOCKS, 256, 0, stream>>>(histG, offG, deg,
                                                tmpExc, bsum, bOff, scounter);

    k_scatter<<<E4B, 256, 0, stream>>>(ei, rank, offG,
                                       tmpExc, bOff, srcs);

    int k3_blocks = (N_NODES + 3) / 4;   // 12500, one wave per node
    k3_gather<<<k3_blocks, 256, 0, stream>>>(tmpExc, bOff, deg, srcs,
                                             ssrc, strg, projb, outv);
}